// Round 17
// baseline (520.281 us; speedup 1.0000x reference)
//
#include <hip/hip_runtime.h>
#include <hip/hip_cooperative_groups.h>
#include <hip/hip_bf16.h>
#include <cstddef>

namespace cg = cooperative_groups;

#define TT 512
#define BB 8
#define HH 1024
#define MM 32
#define NVOCAB 32000
#define NROWS (TT * BB)   // 4096

typedef __attribute__((ext_vector_type(8))) short bf16x8;
typedef __attribute__((ext_vector_type(8))) unsigned short u16x8;
typedef __attribute__((ext_vector_type(4))) float f32x4;

__device__ __forceinline__ void gload_lds16(const void* g, void* l) {
    __builtin_amdgcn_global_load_lds(
        (const __attribute__((address_space(1))) void*)g,
        (__attribute__((address_space(3))) void*)l, 16, 0, 0);
}

__device__ __forceinline__ unsigned short bf16_bits(float f) {
    __hip_bfloat16 h = __float2bfloat16(f);
    return *reinterpret_cast<unsigned short*>(&h);
}

__device__ __forceinline__ float bf16_to_f(unsigned short u) {
    unsigned int x = ((unsigned int)u) << 16;
    return *reinterpret_cast<float*>(&x);
}

struct CoopArgs {
    const int* x;
    const float *emb, *pos;
    const float *Wq1, *Wk1, *Wq2, *Wk2, *Wq3, *Wk3;
    const float *W2, *b2, *W3, *b3, *W4, *b4, *Wout;
    const float *ln2g, *ln2b, *ln3g, *ln3b;
    __hip_bfloat16* Wqkt;
    float *dvec, *cvec;
    unsigned int* flg;
    __hip_bfloat16 *W2t, *W3t, *W4t, *Wot;
    float *pa, *pb;
    __hip_bfloat16 *spkb, *hb;
};

// ---------------------------------------------------------------------------
// phase: q/k weight prep (one of 6 tasks; per-block)
// ---------------------------------------------------------------------------
__device__ void d_prep_qk(int z, int tid, char* smem, const CoopArgs& A) {
    float (*rd)[32] = (float(*)[32])smem;
    float (*rc)[32] = (float(*)[32])(smem + 1024);
    int layer = z >> 1, half = z & 1;
    const float* W = (z == 0) ? A.Wq1 : (z == 1) ? A.Wk1 : (z == 2) ? A.Wq2
                   : (z == 3) ? A.Wk2 : (z == 4) ? A.Wq3 : A.Wk3;
    const float* g = (layer == 0) ? nullptr : (layer == 1) ? A.ln2g : A.ln3g;
    const float* b = (layer == 0) ? nullptr : (layer == 1) ? A.ln2b : A.ln3b;

    int c = tid & 31, seg = tid >> 5;
    int row = layer * 64 + half * 32 + c;
    __hip_bfloat16* outp = A.Wqkt + (size_t)row * HH;

    float dpart = 0.f, cpart = 0.f;
    unsigned short buf[8];
    #pragma unroll 2
    for (int blk = 0; blk < 16; ++blk) {
        #pragma unroll
        for (int u = 0; u < 8; ++u) {
            int h = seg * 128 + blk * 8 + u;
            float gv = g ? g[h] : 1.f;
            float bv = b ? b[h] : 0.f;
            float wv = W[(size_t)h * MM + c];
            float wp = gv * wv;
            dpart += wp;
            cpart += bv * wv;
            buf[u] = bf16_bits(wp);
        }
        *(u16x8*)(outp + seg * 128 + blk * 8) = *(u16x8*)buf;
    }
    rd[seg][c] = dpart;
    rc[seg][c] = cpart;
    __syncthreads();
    if (tid < 32) {
        float ds = 0.f, cs = 0.f;
        #pragma unroll
        for (int s2 = 0; s2 < 8; ++s2) { ds += rd[s2][tid]; cs += rc[s2][tid]; }
        A.dvec[layer * 64 + half * 32 + tid] = ds;
        A.cvec[layer * 64 + half * 32 + tid] = cs;
    }
}

// ---------------------------------------------------------------------------
// phase: one 32x32 transpose tile of a mid weight (task t in [0,3072))
// ---------------------------------------------------------------------------
__device__ void d_mid_transpose(int t, int tid, char* smem, const CoopArgs& A) {
    float (*ts)[33] = (float(*)[33])smem;
    int zz = t >> 10;
    int rem = t & 1023;
    int k0 = (rem >> 5) * 32;
    int n0 = (rem & 31) * 32;
    const float* W = (zz == 0) ? A.W2 : (zz == 1) ? A.W3 : A.W4;
    __hip_bfloat16* Wt = (zz == 0) ? A.W2t : (zz == 1) ? A.W3t : A.W4t;
    int tx = tid & 31, ty = tid >> 5;
    __syncthreads();
    #pragma unroll
    for (int r = 0; r < 4; ++r)
        ts[ty + r * 8][tx] = W[(size_t)(k0 + ty + r * 8) * HH + n0 + tx];
    __syncthreads();
    #pragma unroll
    for (int r = 0; r < 4; ++r)
        Wt[(size_t)(n0 + ty + r * 8) * HH + k0 + tx] = __float2bfloat16(ts[tx][ty + r * 8]);
}

// ---------------------------------------------------------------------------
// phase: MFMA projection + (folded LN) + tau-softmax, per-block (64 rows)
// ---------------------------------------------------------------------------
template <int MODE>
__device__ void d_projmm(int bx, int tid, char* smem, unsigned int* sg,
                         const __hip_bfloat16* X, const __hip_bfloat16* Wt,
                         const float* dvec, const float* cvec,
                         const unsigned int* gate,
                         float* aout, float* bout_, const CoopArgs& A) {
    float* smu  = (float*)smem;
    float* sinv = (float*)(smem + 256);
    int lane = tid & 63;
    int rl = lane & 15;

    unsigned int gv = 1u;
    if (MODE == 1 && gate) {
        if (tid == 0) *sg = atomicOr((unsigned int*)gate, 0u);
        __syncthreads();
        gv = *sg;
    }

    if (MODE == 1 && gate && ((gv >> (bx >> 1)) & 1u) == 0u) {
        float v0 = cvec[rl] * 0.5f,      v1 = cvec[rl + 16] * 0.5f;
        float v2 = cvec[rl + 32] * 0.5f, v3 = cvec[rl + 48] * 0.5f;
        float m = fmaxf(v0, v1);
        #pragma unroll
        for (int o = 8; o >= 1; o >>= 1) m = fmaxf(m, __shfl_xor(m, o));
        float e0 = expf(v0 - m), e1 = expf(v1 - m);
        float sm = e0 + e1;
        #pragma unroll
        for (int o = 8; o >= 1; o >>= 1) sm += __shfl_xor(sm, o);
        float qa0 = e0 / sm, qa1 = e1 / sm;
        float mk = fmaxf(v2, v3);
        #pragma unroll
        for (int o = 8; o >= 1; o >>= 1) mk = fmaxf(mk, __shfl_xor(mk, o));
        float f0 = expf(v2 - mk), f1 = expf(v3 - mk);
        float sk = f0 + f1;
        #pragma unroll
        for (int o = 8; o >= 1; o >>= 1) sk += __shfl_xor(sk, o);
        float kb0 = f0 / sk, kb1 = f1 / sk;
        int wid = tid >> 4;
        for (int rr = wid; rr < 64; rr += 16) {
            size_t r = (size_t)bx * 64 + rr;
            aout[r * MM + rl]       = qa0;
            aout[r * MM + rl + 16]  = qa1;
            bout_[r * MM + rl]      = kb0;
            bout_[r * MM + rl + 16] = kb1;
        }
        return;
    }

    int w = tid >> 6;
    int rbase = bx * 64 + w * 16;
    int kg = lane >> 4;
    int rr_ = rbase + rl;

    const __hip_bfloat16* Ap = X + (size_t)rr_ * HH + kg * 8;
    const float* ep = nullptr;
    const float* pp = nullptr;
    if (MODE == 0) {
        int idx = A.x[rr_];
        ep = A.emb + (size_t)idx * HH + kg * 8;
        pp = A.pos + (size_t)(rr_ >> 3) * HH + kg * 8;
    }
    const __hip_bfloat16* Bp = Wt + (size_t)rl * HH + kg * 8;

    f32x4 acc[4] = {};
    float s = 0.f, ss = 0.f;

    for (int kk = 0; kk < 32; ++kk) {
        bf16x8 a;
        if (MODE == 0) {
            float4 e0 = *(const float4*)(ep + kk * 32);
            float4 e1 = *(const float4*)(ep + kk * 32 + 4);
            float4 p0 = *(const float4*)(pp + kk * 32);
            float4 p1 = *(const float4*)(pp + kk * 32 + 4);
            unsigned short au[8];
            au[0] = bf16_bits(e0.x + p0.x); au[1] = bf16_bits(e0.y + p0.y);
            au[2] = bf16_bits(e0.z + p0.z); au[3] = bf16_bits(e0.w + p0.w);
            au[4] = bf16_bits(e1.x + p1.x); au[5] = bf16_bits(e1.y + p1.y);
            au[6] = bf16_bits(e1.z + p1.z); au[7] = bf16_bits(e1.w + p1.w);
            a = *(bf16x8*)au;
        } else {
            a = *(const bf16x8*)(Ap + kk * 32);
            #pragma unroll
            for (int u = 0; u < 8; ++u) {
                float f = bf16_to_f(((unsigned short*)&a)[u]);
                s += f; ss = fmaf(f, f, ss);
            }
        }
        #pragma unroll
        for (int n = 0; n < 4; ++n) {
            bf16x8 bfrag = *(const bf16x8*)(Bp + (size_t)(n * 16) * HH + kk * 32);
            acc[n] = __builtin_amdgcn_mfma_f32_16x16x32_bf16(a, bfrag, acc[n], 0, 0, 0);
        }
    }

    if (MODE == 1) {
        s += __shfl_down(s, 32); ss += __shfl_down(ss, 32);
        s += __shfl_down(s, 16); ss += __shfl_down(ss, 16);
        if (lane < 16) {
            float mu = s * (1.f / HH);
            float var = ss * (1.f / HH) - mu * mu;
            smu[w * 16 + lane] = mu;
            sinv[w * 16 + lane] = rsqrtf(var + 1e-5f);
        }
        __syncthreads();
    }

    float dv[4], cv[4];
    if (MODE == 1) {
        #pragma unroll
        for (int n = 0; n < 4; ++n) {
            dv[n] = dvec[n * 16 + rl];
            cv[n] = cvec[n * 16 + rl];
        }
    }

    #pragma unroll
    for (int qq = 0; qq < 4; ++qq) {
        int rloc = w * 16 + (lane >> 4) * 4 + qq;
        float v[4];
        if (MODE == 1) {
            float inv = sinv[rloc];
            float muin = smu[rloc] * inv;
            #pragma unroll
            for (int n = 0; n < 4; ++n)
                v[n] = acc[n][qq] * inv - muin * dv[n] + cv[n];
        } else {
            #pragma unroll
            for (int n = 0; n < 4; ++n) v[n] = acc[n][qq];
        }
        size_t r = (size_t)bx * 64 + rloc;

        {
            float v0 = v[0] * 0.5f, v1 = v[1] * 0.5f;
            float m = fmaxf(v0, v1);
            #pragma unroll
            for (int o = 8; o >= 1; o >>= 1) m = fmaxf(m, __shfl_xor(m, o));
            float e0 = expf(v0 - m), e1 = expf(v1 - m);
            float sm = e0 + e1;
            #pragma unroll
            for (int o = 8; o >= 1; o >>= 1) sm += __shfl_xor(sm, o);
            float rs = 1.f / sm;
            aout[r * MM + rl]      = e0 * rs;
            aout[r * MM + rl + 16] = e1 * rs;
        }
        {
            float v0 = v[2] * 0.5f, v1 = v[3] * 0.5f;
            float m = fmaxf(v0, v1);
            #pragma unroll
            for (int o = 8; o >= 1; o >>= 1) m = fmaxf(m, __shfl_xor(m, o));
            float e0 = expf(v0 - m), e1 = expf(v1 - m);
            float sm = e0 + e1;
            #pragma unroll
            for (int o = 8; o >= 1; o >>= 1) sm += __shfl_xor(sm, o);
            float rs = 1.f / sm;
            bout_[r * MM + rl]      = e0 * rs;
            bout_[r * MM + rl + 16] = e1 * rs;
        }
    }
}

// ---------------------------------------------------------------------------
// phase: leaky scan as a WAVE task (64 lanes, CHUNK=64, no block barrier;
// same-wave LDS RAW ordered by lgkmcnt). lds slice: 8704 B per wave.
// ---------------------------------------------------------------------------
__device__ void d_scan_wave(int task, int lane, char* lds,
                            const float* a, const float* bsm,
                            __hip_bfloat16* spk, unsigned int* flg) {
    float* sa = (float*)lds;             // 128 floats
    float* sb = (float*)(lds + 512);     // 64*32 floats
    int bb = task >> 4;
    int ig = task & 15;
    int i2 = lane >> 5, j = lane & 31;
    int i = ig * 2 + i2;
    float mem = 0.f;
    unsigned int pm = 0u;
    for (int t0 = 0; t0 < TT; t0 += 64) {
        for (int v = lane; v < 64 * 8; v += 64) {
            int tt = v >> 3, p = v & 7;
            ((float4*)sb)[v] = ((const float4*)bsm)[((size_t)(t0 + tt) * BB + bb) * 8 + p];
        }
        for (int v = lane; v < 128; v += 64) {
            int tt = v >> 1, ii = v & 1;
            sa[v] = a[((size_t)(t0 + tt) * BB + bb) * MM + ig * 2 + ii];
        }
        for (int tt = 0; tt < 64; ++tt) {
            float av = sa[tt * 2 + i2];
            float bv = sb[tt * MM + j];
            mem = fmaf(0.9f, mem, av * bv);
            float sv = (mem > 1.0f) ? 1.0f : 0.0f;
            pm |= (sv != 0.f) ? (1u << ((t0 + tt) >> 4)) : 0u;
            spk[((size_t)(t0 + tt) * BB + bb) * HH + i * MM + j] = __float2bfloat16(sv);
            mem -= sv;
        }
    }
    #pragma unroll
    for (int o = 32; o >= 1; o >>= 1) pm |= __shfl_xor(pm, o);
    if (lane == 0 && pm) atomicOr(flg, pm);
}

// ---------------------------------------------------------------------------
// phase: mid bf16 MFMA GEMM (one 128x128 tile; bx in [0,8), by in [0,32))
// ---------------------------------------------------------------------------
__device__ void d_gemm_mid(int bx, int by, int tid, char* smem, unsigned int* sg,
                           const __hip_bfloat16* Ain, const __hip_bfloat16* Bt,
                           const float* bias, __hip_bfloat16* Cb,
                           const unsigned int* gin, unsigned int* gout_) {
    const int N = HH, K = HH;
    int brow = by * 128;
    int bcol = bx * 128;

    if (tid == 0) *sg = atomicOr((unsigned int*)gin, 0u);
    __syncthreads();
    unsigned int gv = *sg;

    if (((gv >> by) & 1u) == 0u) {
        int col = bcol + (tid & 31) * 4;
        float4 bv = *(const float4*)(bias + col);
        ushort4 o;
        o.x = bf16_bits(fmaxf(bv.x, 0.f));
        o.y = bf16_bits(fmaxf(bv.y, 0.f));
        o.z = bf16_bits(fmaxf(bv.z, 0.f));
        o.w = bf16_bits(fmaxf(bv.w, 0.f));
        for (int r = tid >> 5; r < 128; r += 8)
            *(ushort4*)(Cb + (size_t)(brow + r) * N + col) = o;
        unsigned int ab = (unsigned int)(o.x | o.y | o.z | o.w);
        unsigned long long bl = __ballot(ab != 0u);
        if ((tid & 63) == 0 && bl) atomicOr(gout_, 1u << by);
        return;
    }

    __hip_bfloat16* As = (__hip_bfloat16*)smem;
    __hip_bfloat16* Bs = (__hip_bfloat16*)(smem + 8192);
    int lane = tid & 63;
    int w = tid >> 6;
    int wr = w >> 1, wc = w & 1;

    f32x4 acc[4][4] = {};

    const __hip_bfloat16* gA = Ain + (size_t)(brow + (tid >> 2)) * K + (tid & 3) * 8;
    const __hip_bfloat16* gB = Bt  + (size_t)(bcol + (tid >> 2)) * K + (tid & 3) * 8;
    __hip_bfloat16* lA0 = As + (size_t)(w * 512);
    __hip_bfloat16* lB0 = Bs + (size_t)(w * 512);
    const size_t rstep = (size_t)64 * K;

    int r0 = wr * 64 + (lane & 15);
    int c0 = wc * 64 + (lane & 15);
    int kb = lane >> 4;

    for (int k0 = 0; k0 < K; k0 += 32) {
        gload_lds16(gA + k0,         lA0);
        gload_lds16(gA + k0 + rstep, lA0 + 2048);
        gload_lds16(gB + k0,         lB0);
        gload_lds16(gB + k0 + rstep, lB0 + 2048);
        __syncthreads();

        bf16x8 af[4], bfr[4];
        #pragma unroll
        for (int m = 0; m < 4; ++m)
            af[m] = ((const bf16x8*)As)[(r0 + m * 16) * 4 + kb];
        #pragma unroll
        for (int n = 0; n < 4; ++n)
            bfr[n] = ((const bf16x8*)Bs)[(c0 + n * 16) * 4 + kb];
        #pragma unroll
        for (int m = 0; m < 4; ++m)
            #pragma unroll
            for (int n = 0; n < 4; ++n)
                acc[m][n] = __builtin_amdgcn_mfma_f32_16x16x32_bf16(af[m], bfr[n], acc[m][n], 0, 0, 0);
        __syncthreads();
    }

    int ccol = bcol + wc * 64 + (lane & 15);
    int crow = brow + wr * 64 + ((lane >> 4) << 2);
    unsigned int fb = 0u;
    #pragma unroll
    for (int n = 0; n < 4; ++n) {
        float bv = bias[ccol + n * 16];
        #pragma unroll
        for (int m = 0; m < 4; ++m) {
            #pragma unroll
            for (int q2 = 0; q2 < 4; ++q2) {
                float v = fmaxf(acc[m][n][q2] + bv, 0.f);
                unsigned short ub = bf16_bits(v);
                fb |= (unsigned int)ub;
                *(unsigned short*)(Cb + (size_t)(crow + m * 16 + q2) * N + ccol + n * 16) = ub;
            }
        }
    }
    unsigned long long bl = __ballot(fb != 0u);
    if ((tid & 63) == 0 && bl) atomicOr(gout_, 1u << by);
}

// ---------------------------------------------------------------------------
// phase: one 64-col strip of the Wout transpose (32 k-tiles)
// ---------------------------------------------------------------------------
__device__ void d_cvt_strip(int strip, int tid, char* smem, const CoopArgs& A) {
    float (*t)[68] = (float(*)[68])smem;
    const int K = HH, N = NVOCAB;
    int n0 = strip * 64;
    for (int k0 = 0; k0 < K; k0 += 32) {
        __syncthreads();
        #pragma unroll
        for (int it = 0; it < 2; ++it) {
            int idx = tid + it * 256;
            int kk = idx >> 4;
            int nn = (idx & 15) * 4;
            *(float4*)&t[kk][nn] = *(const float4*)(A.Wout + (size_t)(k0 + kk) * N + n0 + nn);
        }
        __syncthreads();
        int nn = tid >> 2;
        int kc = (tid & 3) * 8;
        u16x8 o;
        #pragma unroll
        for (int u = 0; u < 8; ++u) o[u] = bf16_bits(t[kc + u][nn]);
        *(u16x8*)(A.Wot + (size_t)(n0 + nn) * K + k0 + kc) = o;
    }
}

// ---------------------------------------------------------------------------
// THE cooperative mega-kernel: setup + 3x(proj, scan, gemm) + gated cvt.
// 256 blocks x 256 threads (1 block/CU), 10 grid syncs.
// ---------------------------------------------------------------------------
__global__ __launch_bounds__(256) void k_coop(CoopArgs A) {
    cg::grid_group grid = cg::this_grid();
    __shared__ __align__(16) char smem[34816];
    __shared__ unsigned int sgate;
    int bid = blockIdx.x;
    int tid = threadIdx.x;
    int w = tid >> 6, lane = tid & 63;

    // P0: setup (qk prep on blocks 0-5; mid transposes on blocks 6-255)
    if (bid == 0 && tid < 8) atomicExch(A.flg + tid, 0u);
    if (bid < 6) d_prep_qk(bid, tid, smem, A);
    else for (int t = bid - 6; t < 3072; t += 250) d_mid_transpose(t, tid, smem, A);
    grid.sync();

    // P1: projmm layer 1 (embed-fused)
    if (bid < 64)
        d_projmm<0>(bid, tid, smem, &sgate, nullptr, A.Wqkt,
                    nullptr, nullptr, nullptr, A.pa, A.pb, A);
    grid.sync();

    // P2: scan layer 1
    { int task = bid * 4 + w;
      if (task < 128) d_scan_wave(task, lane, smem + w * 8704, A.pa, A.pb, A.spkb, A.flg + 0); }
    grid.sync();

    // P3: gemm layer 1 (spkb @ W2t -> hb)
    d_gemm_mid(bid & 7, bid >> 3, tid, smem, &sgate, A.spkb, A.W2t, A.b2, A.hb,
               A.flg + 0, A.flg + 1);
    grid.sync();

    // P4: projmm layer 2
    if (bid < 64)
        d_projmm<1>(bid, tid, smem, &sgate, A.hb, A.Wqkt + (size_t)64 * HH,
                    A.dvec + 64, A.cvec + 64, A.flg + 1, A.pa, A.pb, A);
    grid.sync();

    // P5: scan layer 2
    { int task = bid * 4 + w;
      if (task < 128) d_scan_wave(task, lane, smem + w * 8704, A.pa, A.pb, A.spkb, A.flg + 2); }
    grid.sync();

    // P6: gemm layer 2
    d_gemm_mid(bid & 7, bid >> 3, tid, smem, &sgate, A.spkb, A.W3t, A.b3, A.hb,
               A.flg + 2, A.flg + 3);
    grid.sync();

    // P7: projmm layer 3
    if (bid < 64)
        d_projmm<1>(bid, tid, smem, &sgate, A.hb, A.Wqkt + (size_t)128 * HH,
                    A.dvec + 128, A.cvec + 128, A.flg + 3, A.pa, A.pb, A);
    grid.sync();

    // P8: scan layer 3
    { int task = bid * 4 + w;
      if (task < 128) d_scan_wave(task, lane, smem + w * 8704, A.pa, A.pb, A.spkb, A.flg + 4); }
    grid.sync();

    // P9: gemm layer 3
    d_gemm_mid(bid & 7, bid >> 3, tid, smem, &sgate, A.spkb, A.W4t, A.b4, A.hb,
               A.flg + 4, A.flg + 5);
    grid.sync();

    // P10: gated Wout transpose (500 strips; ~free when silent)
    if (tid == 0) sgate = atomicOr(A.flg + 5, 0u);
    __syncthreads();
    if (sgate != 0u)
        for (int s = bid; s < 500; s += 256) d_cvt_strip(s, tid, smem, A);
}

// ---------------------------------------------------------------------------
// final GEMM (R8 config) gated per 256-row tile (bits 2y, 2y+1). Separate
// ordinary launch (kernel-boundary coherence covers plain flag read).
// ---------------------------------------------------------------------------
__global__ __launch_bounds__(512, 2) void k_gemm_big(const __hip_bfloat16* __restrict__ A,
                                                     const __hip_bfloat16* __restrict__ Bt,
                                                     const float* __restrict__ bias,
                                                     float* __restrict__ C,
                                                     int N, int K,
                                                     const unsigned int* __restrict__ gate) {
    int tid = threadIdx.x;
    int brow = blockIdx.y * 256;
    int bcol = blockIdx.x * 256;

    if (gate && (((*gate) >> (blockIdx.y * 2)) & 3u) == 0u) {
        int col = bcol + (tid & 63) * 4;
        float4 bv = *(const float4*)(bias + col);
        for (int r = tid >> 6; r < 256; r += 8)
            *(float4*)(C + (size_t)(brow + r) * N + col) = bv;
        return;
    }

    __shared__ __align__(16) char lds[3 * 32768];
    int lane = tid & 63;
    int w = tid >> 6;
    int wr = w >> 2;
    int wc = w & 3;

    f32x4 acc[8][4] = {};

    int tsw = tid ^ ((tid >> 3) & 7);
    int rS = tsw >> 2;
    int kS = (tsw & 3) * 8;
    const __hip_bfloat16* gA0 = A  + (size_t)(brow + rS) * K + kS;
    const __hip_bfloat16* gA1 = gA0 + (size_t)128 * K;
    const __hip_bfloat16* gB0 = Bt + (size_t)(bcol + rS) * K + kS;
    const __hip_bfloat16* gB1 = gB0 + (size_t)128 * K;
    char* ldsw = lds + w * 1024;

#define STAGE256(t, q) do {                                          \
        const int kb_ = (t) * 32;                                    \
        gload_lds16(gA0 + kb_, ldsw + (q) * 32768);                  \
        gload_lds16(gA1 + kb_, ldsw + (q) * 32768 + 8192);           \
        gload_lds16(gB0 + kb_, ldsw + (q) * 32768 + 16384);          \
        gload_lds16(gB1 + kb_, ldsw + (q) * 32768 + 24576);          \
    } while (0)

    int r0 = lane & 15;
    int kg = lane >> 4;
    int xr = ((r0 >> 1) & 7) << 4;
    int baseA = (((wr * 128 + r0) * 64) + kg * 16) ^ xr;
    int baseB = (((wc * 64  + r0) * 64) + kg * 16) ^ xr;

    const int NT = K / 32;

    STAGE256(0, 0);
    STAGE256(1, 1);

    int q = 0, qs = 2;
    for (int t = 0; t < NT; ++t) {
        if (t < NT - 1) asm volatile("s_waitcnt vmcnt(4)" ::: "memory");
        else            asm volatile("s_waitcnt vmcnt(0)" ::: "memory");
        __builtin_amdgcn_s_barrier();
        if (t + 2 < NT) {
            STAGE256(t + 2, qs);
            qs = (qs == 2) ? 0 : qs + 1;
        }

        const char* Ab = lds + q * 32768;
        const char* Bb = Ab + 16384;
        q = (q == 2) ? 0 : q + 1;

        bf16x8 af[8], bfr[4];
        #pragma unroll
        for (int m = 0; m < 8; ++m) af[m]  = *(const bf16x8*)(Ab + baseA + m * 1024);
        #pragma unroll
        for (int n = 0; n < 4; ++n) bfr[n] = *(const bf16x8*)(Bb + baseB + n * 1024);

        __builtin_amdgcn_s_setprio(1);
        #pragma unroll
        for (int m = 0; m < 8; ++m)
            #pragma unroll
            for (int n = 0; n < 4; ++n)
                acc[m][n] = __builtin_amdgcn_mfma_f32_16x16x32_bf16(af[m], bfr[n], acc[m][n], 0, 0, 0);
        __builtin_amdgcn_s_setprio(0);
    }
#undef STAGE256

    int ccol = bcol + wc * 64 + (lane & 15);
    int crow = brow + wr * 128 + ((lane >> 4) << 2);
    #pragma unroll
    for (int n = 0; n < 4; ++n) {
        float bv = bias[ccol + n * 16];
        #pragma unroll
        for (int m = 0; m < 8; ++m) {
            #pragma unroll
            for (int q2 = 0; q2 < 4; ++q2) {
                float v = acc[m][n][q2] + bv;
                C[(size_t)(crow + m * 16 + q2) * N + ccol + n * 16] = v;
            }
        }
    }
}

// ---------------------------------------------------------------------------
extern "C" void kernel_launch(void* const* d_in, const int* in_sizes, int n_in,
                              void* d_out, int out_size, void* d_ws, size_t ws_size,
                              hipStream_t stream) {
    const int*   x    = (const int*)d_in[0];
    const float* emb  = (const float*)d_in[1];
    const float* pos  = (const float*)d_in[2];
    const float* Wq1  = (const float*)d_in[3];
    const float* Wk1  = (const float*)d_in[4];
    const float* Wq2  = (const float*)d_in[5];
    const float* Wk2  = (const float*)d_in[6];
    const float* Wq3  = (const float*)d_in[7];
    const float* Wk3  = (const float*)d_in[8];
    const float* W2   = (const float*)d_in[9];
    const float* b2   = (const float*)d_in[10];
    const float* W3   = (const float*)d_in[11];
    const float* b3   = (const float*)d_in[12];
    const float* W4   = (const float*)d_in[13];
    const float* b4   = (const float*)d_in[14];
    const float* Wout = (const float*)d_in[15];
    const float* bout = (const float*)d_in[16];
    const float* ln2g = (const float*)d_in[17];
    const float* ln2b = (const float*)d_in[18];
    const float* ln3g = (const float*)d_in[19];
    const float* ln3b = (const float*)d_in[20];

    char* wsp = (char*)d_ws;
    float* pa  = (float*)wsp;                    wsp += (size_t)NROWS * MM * 4;
    float* pb  = (float*)wsp;                    wsp += (size_t)NROWS * MM * 4;
    float* dvec = (float*)wsp;                   wsp += 192 * 4;
    float* cvec = (float*)wsp;                   wsp += 192 * 4;
    unsigned int* flg = (unsigned int*)wsp;      wsp += 8 * 4;
    __hip_bfloat16* spkb = (__hip_bfloat16*)wsp; wsp += (size_t)NROWS * HH * 2;
    __hip_bfloat16* hb   = (__hip_bfloat16*)wsp; wsp += (size_t)NROWS * HH * 2;
    __hip_bfloat16* Wqkt = (__hip_bfloat16*)wsp; wsp += (size_t)3 * 64 * HH * 2;
    __hip_bfloat16* W2t  = (__hip_bfloat16*)wsp; wsp += (size_t)HH * HH * 2;
    __hip_bfloat16* W3t  = (__hip_bfloat16*)wsp; wsp += (size_t)HH * HH * 2;
    __hip_bfloat16* W4t  = (__hip_bfloat16*)wsp; wsp += (size_t)HH * HH * 2;
    __hip_bfloat16* Wot  = (__hip_bfloat16*)wsp; wsp += (size_t)NVOCAB * HH * 2;
    float* out = (float*)d_out;

    CoopArgs ca;
    ca.x = x; ca.emb = emb; ca.pos = pos;
    ca.Wq1 = Wq1; ca.Wk1 = Wk1; ca.Wq2 = Wq2; ca.Wk2 = Wk2; ca.Wq3 = Wq3; ca.Wk3 = Wk3;
    ca.W2 = W2; ca.b2 = b2; ca.W3 = W3; ca.b3 = b3; ca.W4 = W4; ca.b4 = b4;
    ca.Wout = Wout;
    ca.ln2g = ln2g; ca.ln2b = ln2b; ca.ln3g = ln3g; ca.ln3b = ln3b;
    ca.Wqkt = Wqkt; ca.dvec = dvec; ca.cvec = cvec; ca.flg = flg;
    ca.W2t = W2t; ca.W3t = W3t; ca.W4t = W4t; ca.Wot = Wot;
    ca.pa = pa; ca.pb = pb; ca.spkb = spkb; ca.hb = hb;

    void* kargs[] = { &ca };
    hipLaunchCooperativeKernel((void*)k_coop, dim3(256), dim3(256), kargs, 0, stream);

    dim3 gout(NVOCAB / 256, NROWS / 256);      // (cols=125, rows=16) col-fastest
    k_gemm_big<<<gout, 512, 0, stream>>>(hb, Wot, bout, out, NVOCAB, HH, flg + 5);
}

// Round 18
// 305.602 us; speedup vs baseline: 1.7025x; 1.7025x over previous
//
#include <hip/hip_runtime.h>
#include <hip/hip_bf16.h>
#include <cstddef>

#define TT 512
#define BB 8
#define HH 1024
#define MM 32
#define NVOCAB 32000
#define NROWS (TT * BB)   // 4096

typedef __attribute__((ext_vector_type(8))) short bf16x8;
typedef __attribute__((ext_vector_type(8))) unsigned short u16x8;
typedef __attribute__((ext_vector_type(4))) float f32x4;

__device__ __forceinline__ void gload_lds16(const void* g, void* l) {
    __builtin_amdgcn_global_load_lds(
        (const __attribute__((address_space(1))) void*)g,
        (__attribute__((address_space(3))) void*)l, 16, 0, 0);
}

__device__ __forceinline__ unsigned short bf16_bits(float f) {
    __hip_bfloat16 h = __float2bfloat16(f);
    return *reinterpret_cast<unsigned short*>(&h);
}

__device__ __forceinline__ float bf16_to_f(unsigned short u) {
    unsigned int x = ((unsigned int)u) << 16;
    return *reinterpret_cast<float*>(&x);
}

// ---------------------------------------------------------------------------
// 0) k_setup: merged independent prep work, one launch.
//    blocks [0,6): q/k weight prep (W't bf16, dvec, cvec; block 0 zeroes flags)
//    blocks [6,3078): 3 mid weights fp32 -> bf16 transposed
// ---------------------------------------------------------------------------
__global__ __launch_bounds__(256) void k_setup(const float* __restrict__ Wq1,
                                               const float* __restrict__ Wk1,
                                               const float* __restrict__ Wq2,
                                               const float* __restrict__ Wk2,
                                               const float* __restrict__ Wq3,
                                               const float* __restrict__ Wk3,
                                               const float* __restrict__ ln2g,
                                               const float* __restrict__ ln2b,
                                               const float* __restrict__ ln3g,
                                               const float* __restrict__ ln3b,
                                               const float* __restrict__ W2,
                                               const float* __restrict__ W3,
                                               const float* __restrict__ W4,
                                               __hip_bfloat16* __restrict__ Wqkt,
                                               float* __restrict__ dvec,
                                               float* __restrict__ cvec,
                                               unsigned int* __restrict__ flg,
                                               __hip_bfloat16* __restrict__ W2t,
                                               __hip_bfloat16* __restrict__ W3t,
                                               __hip_bfloat16* __restrict__ W4t) {
    __shared__ __align__(16) char smem[4352];
    int bid = blockIdx.x;
    int tid = threadIdx.x;

    if (bid < 6) {
        float (*rd)[32] = (float(*)[32])smem;
        float (*rc)[32] = (float(*)[32])(smem + 1024);
        int z = bid;
        if (z == 0 && tid < 8) flg[tid] = 0u;
        int layer = z >> 1, half = z & 1;
        const float* W = (z == 0) ? Wq1 : (z == 1) ? Wk1 : (z == 2) ? Wq2
                       : (z == 3) ? Wk2 : (z == 4) ? Wq3 : Wk3;
        const float* g = (layer == 0) ? nullptr : (layer == 1) ? ln2g : ln3g;
        const float* b = (layer == 0) ? nullptr : (layer == 1) ? ln2b : ln3b;

        int c = tid & 31, seg = tid >> 5;
        int row = layer * 64 + half * 32 + c;
        __hip_bfloat16* outp = Wqkt + (size_t)row * HH;

        float dpart = 0.f, cpart = 0.f;
        unsigned short buf[8];
        #pragma unroll 2
        for (int blk = 0; blk < 16; ++blk) {
            #pragma unroll
            for (int u = 0; u < 8; ++u) {
                int h = seg * 128 + blk * 8 + u;
                float gv = g ? g[h] : 1.f;
                float bv = b ? b[h] : 0.f;
                float wv = W[(size_t)h * MM + c];
                float wp = gv * wv;
                dpart += wp;
                cpart += bv * wv;
                buf[u] = bf16_bits(wp);
            }
            *(u16x8*)(outp + seg * 128 + blk * 8) = *(u16x8*)buf;
        }
        rd[seg][c] = dpart;
        rc[seg][c] = cpart;
        __syncthreads();
        if (tid < 32) {
            float ds = 0.f, cs = 0.f;
            #pragma unroll
            for (int s2 = 0; s2 < 8; ++s2) { ds += rd[s2][tid]; cs += rc[s2][tid]; }
            dvec[layer * 64 + half * 32 + tid] = ds;
            cvec[layer * 64 + half * 32 + tid] = cs;
        }
        return;
    }

    // mid-weight transpose: 3 x 1024 tiles of 32x32
    float (*t)[33] = (float(*)[33])smem;
    int q = bid - 6;
    int zz = q >> 10;               // 0..2
    int rem = q & 1023;
    int k0 = (rem >> 5) * 32;
    int n0 = (rem & 31) * 32;
    const float* W = (zz == 0) ? W2 : (zz == 1) ? W3 : W4;
    __hip_bfloat16* Wt = (zz == 0) ? W2t : (zz == 1) ? W3t : W4t;
    int tx = tid & 31, ty = tid >> 5;
    #pragma unroll
    for (int r = 0; r < 4; ++r)
        t[ty + r * 8][tx] = W[(size_t)(k0 + ty + r * 8) * HH + n0 + tx];
    __syncthreads();
    #pragma unroll
    for (int r = 0; r < 4; ++r)
        Wt[(size_t)(n0 + ty + r * 8) * HH + k0 + tx] = __float2bfloat16(t[tx][ty + r * 8]);
}

// ---------------------------------------------------------------------------
// 1) MFMA projection + tau-softmax.
//    MODE 0: A-frags computed on the fly from emb[x[r]] + pos[t] (embed fused,
//            no LN, no gate). MODE 1: A from bf16 X, folded LN, panel gate.
// ---------------------------------------------------------------------------
template <int MODE>
__global__ __launch_bounds__(256) void k_projmm(const int* __restrict__ xw,
                                                const float* __restrict__ emb,
                                                const float* __restrict__ pos,
                                                const __hip_bfloat16* __restrict__ X,
                                                const __hip_bfloat16* __restrict__ Wt,
                                                const float* __restrict__ dvec,
                                                const float* __restrict__ cvec,
                                                const unsigned int* __restrict__ gate,
                                                float* __restrict__ aout,
                                                float* __restrict__ bout_) {
    __shared__ float smu[64], sinv[64];
    int tid = threadIdx.x;
    int lane = tid & 63;
    int rl = lane & 15;

    if (MODE == 1 && gate && (((*gate) >> (blockIdx.x >> 1)) & 1u) == 0u) {
        float v0 = cvec[rl] * 0.5f,      v1 = cvec[rl + 16] * 0.5f;
        float v2 = cvec[rl + 32] * 0.5f, v3 = cvec[rl + 48] * 0.5f;
        float m = fmaxf(v0, v1);
        #pragma unroll
        for (int o = 8; o >= 1; o >>= 1) m = fmaxf(m, __shfl_xor(m, o));
        float e0 = expf(v0 - m), e1 = expf(v1 - m);
        float sm = e0 + e1;
        #pragma unroll
        for (int o = 8; o >= 1; o >>= 1) sm += __shfl_xor(sm, o);
        float qa0 = e0 / sm, qa1 = e1 / sm;
        float mk = fmaxf(v2, v3);
        #pragma unroll
        for (int o = 8; o >= 1; o >>= 1) mk = fmaxf(mk, __shfl_xor(mk, o));
        float f0 = expf(v2 - mk), f1 = expf(v3 - mk);
        float sk = f0 + f1;
        #pragma unroll
        for (int o = 8; o >= 1; o >>= 1) sk += __shfl_xor(sk, o);
        float kb0 = f0 / sk, kb1 = f1 / sk;
        int wid = tid >> 4;
        for (int rr = wid; rr < 64; rr += 16) {
            size_t r = (size_t)blockIdx.x * 64 + rr;
            aout[r * MM + rl]       = qa0;
            aout[r * MM + rl + 16]  = qa1;
            bout_[r * MM + rl]      = kb0;
            bout_[r * MM + rl + 16] = kb1;
        }
        return;
    }

    int w = tid >> 6;
    int rbase = blockIdx.x * 64 + w * 16;
    int kg = lane >> 4;
    int rr_ = rbase + rl;

    const __hip_bfloat16* Ap = X + (size_t)rr_ * HH + kg * 8;   // MODE 1
    const float* ep = nullptr;
    const float* pp = nullptr;
    if (MODE == 0) {
        int idx = xw[rr_];
        ep = emb + (size_t)idx * HH + kg * 8;
        pp = pos + (size_t)(rr_ >> 3) * HH + kg * 8;
    }
    const __hip_bfloat16* Bp = Wt + (size_t)rl * HH + kg * 8;

    f32x4 acc[4] = {};
    float s = 0.f, ss = 0.f;

    for (int kk = 0; kk < 32; ++kk) {
        bf16x8 a;
        if (MODE == 0) {
            float4 e0 = *(const float4*)(ep + kk * 32);
            float4 e1 = *(const float4*)(ep + kk * 32 + 4);
            float4 p0 = *(const float4*)(pp + kk * 32);
            float4 p1 = *(const float4*)(pp + kk * 32 + 4);
            unsigned short au[8];
            au[0] = bf16_bits(e0.x + p0.x); au[1] = bf16_bits(e0.y + p0.y);
            au[2] = bf16_bits(e0.z + p0.z); au[3] = bf16_bits(e0.w + p0.w);
            au[4] = bf16_bits(e1.x + p1.x); au[5] = bf16_bits(e1.y + p1.y);
            au[6] = bf16_bits(e1.z + p1.z); au[7] = bf16_bits(e1.w + p1.w);
            a = *(bf16x8*)au;
        } else {
            a = *(const bf16x8*)(Ap + kk * 32);
            #pragma unroll
            for (int u = 0; u < 8; ++u) {
                float f = bf16_to_f(((unsigned short*)&a)[u]);
                s += f; ss = fmaf(f, f, ss);
            }
        }
        #pragma unroll
        for (int n = 0; n < 4; ++n) {
            bf16x8 bfrag = *(const bf16x8*)(Bp + (size_t)(n * 16) * HH + kk * 32);
            acc[n] = __builtin_amdgcn_mfma_f32_16x16x32_bf16(a, bfrag, acc[n], 0, 0, 0);
        }
    }

    if (MODE == 1) {
        s += __shfl_down(s, 32); ss += __shfl_down(ss, 32);
        s += __shfl_down(s, 16); ss += __shfl_down(ss, 16);
        if (lane < 16) {
            float mu = s * (1.f / HH);
            float var = ss * (1.f / HH) - mu * mu;
            smu[w * 16 + lane] = mu;
            sinv[w * 16 + lane] = rsqrtf(var + 1e-5f);
        }
        __syncthreads();
    }

    float dv[4], cv[4];
    if (MODE == 1) {
        #pragma unroll
        for (int n = 0; n < 4; ++n) {
            dv[n] = dvec[n * 16 + rl];
            cv[n] = cvec[n * 16 + rl];
        }
    }

    #pragma unroll
    for (int qq = 0; qq < 4; ++qq) {
        int rloc = w * 16 + (lane >> 4) * 4 + qq;
        float v[4];
        if (MODE == 1) {
            float inv = sinv[rloc];
            float muin = smu[rloc] * inv;
            #pragma unroll
            for (int n = 0; n < 4; ++n)
                v[n] = acc[n][qq] * inv - muin * dv[n] + cv[n];
        } else {
            #pragma unroll
            for (int n = 0; n < 4; ++n) v[n] = acc[n][qq];
        }
        size_t r = (size_t)blockIdx.x * 64 + rloc;

        {
            float v0 = v[0] * 0.5f, v1 = v[1] * 0.5f;
            float m = fmaxf(v0, v1);
            #pragma unroll
            for (int o = 8; o >= 1; o >>= 1) m = fmaxf(m, __shfl_xor(m, o));
            float e0 = expf(v0 - m), e1 = expf(v1 - m);
            float sm = e0 + e1;
            #pragma unroll
            for (int o = 8; o >= 1; o >>= 1) sm += __shfl_xor(sm, o);
            float rs = 1.f / sm;
            aout[r * MM + rl]      = e0 * rs;
            aout[r * MM + rl + 16] = e1 * rs;
        }
        {
            float v0 = v[2] * 0.5f, v1 = v[3] * 0.5f;
            float m = fmaxf(v0, v1);
            #pragma unroll
            for (int o = 8; o >= 1; o >>= 1) m = fmaxf(m, __shfl_xor(m, o));
            float e0 = expf(v0 - m), e1 = expf(v1 - m);
            float sm = e0 + e1;
            #pragma unroll
            for (int o = 8; o >= 1; o >>= 1) sm += __shfl_xor(sm, o);
            float rs = 1.f / sm;
            bout_[r * MM + rl]      = e0 * rs;
            bout_[r * MM + rl + 16] = e1 * rs;
        }
    }
}

// ---------------------------------------------------------------------------
// 2) leaky scan -> bf16 spikes + fused activity bitmask (bit p = t>>4).
// ---------------------------------------------------------------------------
#define CHUNK 128
__global__ __launch_bounds__(64) void k_scan(const float* __restrict__ a,
                                             const float* __restrict__ bsm,
                                             __hip_bfloat16* __restrict__ spk,
                                             unsigned int* __restrict__ flg) {
    __shared__ float sa[CHUNK * 2];
    __shared__ float sb[CHUNK * MM];
    int bb = blockIdx.x >> 4;
    int ig = blockIdx.x & 15;
    int tid = threadIdx.x;
    int i2 = tid >> 5, j = tid & 31;
    int i = ig * 2 + i2;
    float mem = 0.f;
    unsigned int pm = 0u;
    for (int t0 = 0; t0 < TT; t0 += CHUNK) {
        __syncthreads();
        for (int v = tid; v < CHUNK * 8; v += 64) {
            int tt = v >> 3, p = v & 7;
            ((float4*)sb)[v] = ((const float4*)bsm)[((size_t)(t0 + tt) * BB + bb) * 8 + p];
        }
        for (int v = tid; v < CHUNK * 2; v += 64) {
            int tt = v >> 1, ii = v & 1;
            sa[v] = a[((size_t)(t0 + tt) * BB + bb) * MM + ig * 2 + ii];
        }
        __syncthreads();
        for (int tt = 0; tt < CHUNK; ++tt) {
            float av = sa[tt * 2 + i2];
            float bv = sb[tt * MM + j];
            mem = fmaf(0.9f, mem, av * bv);
            float sv = (mem > 1.0f) ? 1.0f : 0.0f;
            pm |= (sv != 0.f) ? (1u << ((t0 + tt) >> 4)) : 0u;
            spk[((size_t)(t0 + tt) * BB + bb) * HH + i * MM + j] = __float2bfloat16(sv);
            mem -= sv;
        }
    }
    #pragma unroll
    for (int o = 32; o >= 1; o >>= 1) pm |= __shfl_xor(pm, o);
    if (tid == 0 && pm) atomicOr(flg, pm);
}

// ---------------------------------------------------------------------------
// 3) Wout fp32 [K][N] -> bf16 [N][K], gated; 500 blocks, each a 64-col strip
//    looping all 32 k-tiles (cheap early-return when silent).
// ---------------------------------------------------------------------------
__global__ __launch_bounds__(256) void k_transpose_cvt_v4(const float* __restrict__ W,
                                                          __hip_bfloat16* __restrict__ Wt,
                                                          int K, int N,
                                                          const unsigned int* __restrict__ flg) {
    if (flg && *flg == 0u) return;
    __shared__ float t[32][68];
    int n0 = blockIdx.x * 64;
    int tid = threadIdx.x;
    for (int k0 = 0; k0 < K; k0 += 32) {
        __syncthreads();
        #pragma unroll
        for (int it = 0; it < 2; ++it) {
            int idx = tid + it * 256;
            int kk = idx >> 4;
            int nn = (idx & 15) * 4;
            *(float4*)&t[kk][nn] = *(const float4*)(W + (size_t)(k0 + kk) * N + n0 + nn);
        }
        __syncthreads();
        int nn = tid >> 2;
        int kc = (tid & 3) * 8;
        u16x8 o;
        #pragma unroll
        for (int u = 0; u < 8; ++u) o[u] = bf16_bits(t[kc + u][nn]);
        *(u16x8*)(Wt + (size_t)(n0 + nn) * K + k0 + kc) = o;
    }
}

// ---------------------------------------------------------------------------
// 4) mid bf16 MFMA GEMM, gated in (bit blockIdx.y), fused out-flag.
// ---------------------------------------------------------------------------
__global__ __launch_bounds__(256) void k_gemm_bf16(const __hip_bfloat16* __restrict__ A,
                                                   const __hip_bfloat16* __restrict__ Bt,
                                                   const float* __restrict__ bias,
                                                   __hip_bfloat16* __restrict__ Cb,
                                                   int N, int K,
                                                   const unsigned int* __restrict__ gin,
                                                   unsigned int* __restrict__ gout_) {
    int tid = threadIdx.x;
    int brow = blockIdx.y * 128;
    int bcol = blockIdx.x * 128;

    if (gin && (((*gin) >> blockIdx.y) & 1u) == 0u) {
        int col = bcol + (tid & 31) * 4;
        float4 bv = *(const float4*)(bias + col);
        ushort4 o;
        o.x = bf16_bits(fmaxf(bv.x, 0.f));
        o.y = bf16_bits(fmaxf(bv.y, 0.f));
        o.z = bf16_bits(fmaxf(bv.z, 0.f));
        o.w = bf16_bits(fmaxf(bv.w, 0.f));
        for (int r = tid >> 5; r < 128; r += 8)
            *(ushort4*)(Cb + (size_t)(brow + r) * N + col) = o;
        unsigned int ab = (unsigned int)(o.x | o.y | o.z | o.w);
        unsigned long long bl = __ballot(ab != 0u);
        if ((tid & 63) == 0 && bl) atomicOr(gout_, 1u << blockIdx.y);
        return;
    }

    __shared__ __align__(16) __hip_bfloat16 As[128 * 32];
    __shared__ __align__(16) __hip_bfloat16 Bs[128 * 32];
    int lane = tid & 63;
    int w = tid >> 6;
    int wr = w >> 1, wc = w & 1;

    f32x4 acc[4][4] = {};

    const __hip_bfloat16* gA = A  + (size_t)(brow + (tid >> 2)) * K + (tid & 3) * 8;
    const __hip_bfloat16* gB = Bt + (size_t)(bcol + (tid >> 2)) * K + (tid & 3) * 8;
    __hip_bfloat16* lA0 = As + (size_t)(w * 512);
    __hip_bfloat16* lB0 = Bs + (size_t)(w * 512);
    const size_t rstep = (size_t)64 * K;

    int r0 = wr * 64 + (lane & 15);
    int c0 = wc * 64 + (lane & 15);
    int kb = lane >> 4;

    for (int k0 = 0; k0 < K; k0 += 32) {
        gload_lds16(gA + k0,         lA0);
        gload_lds16(gA + k0 + rstep, lA0 + 2048);
        gload_lds16(gB + k0,         lB0);
        gload_lds16(gB + k0 + rstep, lB0 + 2048);
        __syncthreads();

        bf16x8 af[4], bfr[4];
        #pragma unroll
        for (int m = 0; m < 4; ++m)
            af[m] = ((const bf16x8*)As)[(r0 + m * 16) * 4 + kb];
        #pragma unroll
        for (int n = 0; n < 4; ++n)
            bfr[n] = ((const bf16x8*)Bs)[(c0 + n * 16) * 4 + kb];
        #pragma unroll
        for (int m = 0; m < 4; ++m)
            #pragma unroll
            for (int n = 0; n < 4; ++n)
                acc[m][n] = __builtin_amdgcn_mfma_f32_16x16x32_bf16(af[m], bfr[n], acc[m][n], 0, 0, 0);
        __syncthreads();
    }

    int ccol = bcol + wc * 64 + (lane & 15);
    int crow = brow + wr * 64 + ((lane >> 4) << 2);
    unsigned int fb = 0u;
    #pragma unroll
    for (int n = 0; n < 4; ++n) {
        float bv = bias[ccol + n * 16];
        #pragma unroll
        for (int m = 0; m < 4; ++m) {
            #pragma unroll
            for (int q2 = 0; q2 < 4; ++q2) {
                float v = fmaxf(acc[m][n][q2] + bv, 0.f);
                unsigned short ub = bf16_bits(v);
                fb |= (unsigned int)ub;
                *(unsigned short*)(Cb + (size_t)(crow + m * 16 + q2) * N + ccol + n * 16) = ub;
            }
        }
    }
    unsigned long long bl = __ballot(fb != 0u);
    if ((tid & 63) == 0 && bl) atomicOr(gout_, 1u << blockIdx.y);
}

// ---------------------------------------------------------------------------
// 5) final GEMM (R8 config) gated per 256-row tile (bits 2y, 2y+1).
// ---------------------------------------------------------------------------
__global__ __launch_bounds__(512, 2) void k_gemm_big(const __hip_bfloat16* __restrict__ A,
                                                     const __hip_bfloat16* __restrict__ Bt,
                                                     const float* __restrict__ bias,
                                                     float* __restrict__ C,
                                                     int N, int K,
                                                     const unsigned int* __restrict__ gate) {
    int tid = threadIdx.x;
    int brow = blockIdx.y * 256;
    int bcol = blockIdx.x * 256;

    if (gate && (((*gate) >> (blockIdx.y * 2)) & 3u) == 0u) {
        int col = bcol + (tid & 63) * 4;
        float4 bv = *(const float4*)(bias + col);
        for (int r = tid >> 6; r < 256; r += 8)
            *(float4*)(C + (size_t)(brow + r) * N + col) = bv;
        return;
    }

    __shared__ __align__(16) char lds[3 * 32768];
    int lane = tid & 63;
    int w = tid >> 6;
    int wr = w >> 2;
    int wc = w & 3;

    f32x4 acc[8][4] = {};

    int tsw = tid ^ ((tid >> 3) & 7);
    int rS = tsw >> 2;
    int kS = (tsw & 3) * 8;
    const __hip_bfloat16* gA0 = A  + (size_t)(brow + rS) * K + kS;
    const __hip_bfloat16* gA1 = gA0 + (size_t)128 * K;
    const __hip_bfloat16* gB0 = Bt + (size_t)(bcol + rS) * K + kS;
    const __hip_bfloat16* gB1 = gB0 + (size_t)128 * K;
    char* ldsw = lds + w * 1024;

#define STAGE256(t, q) do {                                          \
        const int kb_ = (t) * 32;                                    \
        gload_lds16(gA0 + kb_, ldsw + (q) * 32768);                  \
        gload_lds16(gA1 + kb_, ldsw + (q) * 32768 + 8192);           \
        gload_lds16(gB0 + kb_, ldsw + (q) * 32768 + 16384);          \
        gload_lds16(gB1 + kb_, ldsw + (q) * 32768 + 24576);          \
    } while (0)

    int r0 = lane & 15;
    int kg = lane >> 4;
    int xr = ((r0 >> 1) & 7) << 4;
    int baseA = (((wr * 128 + r0) * 64) + kg * 16) ^ xr;
    int baseB = (((wc * 64  + r0) * 64) + kg * 16) ^ xr;

    const int NT = K / 32;

    STAGE256(0, 0);
    STAGE256(1, 1);

    int q = 0, qs = 2;
    for (int t = 0; t < NT; ++t) {
        if (t < NT - 1) asm volatile("s_waitcnt vmcnt(4)" ::: "memory");
        else            asm volatile("s_waitcnt vmcnt(0)" ::: "memory");
        __builtin_amdgcn_s_barrier();
        if (t + 2 < NT) {
            STAGE256(t + 2, qs);
            qs = (qs == 2) ? 0 : qs + 1;
        }

        const char* Ab = lds + q * 32768;
        const char* Bb = Ab + 16384;
        q = (q == 2) ? 0 : q + 1;

        bf16x8 af[8], bfr[4];
        #pragma unroll
        for (int m = 0; m < 8; ++m) af[m]  = *(const bf16x8*)(Ab + baseA + m * 1024);
        #pragma unroll
        for (int n = 0; n < 4; ++n) bfr[n] = *(const bf16x8*)(Bb + baseB + n * 1024);

        __builtin_amdgcn_s_setprio(1);
        #pragma unroll
        for (int m = 0; m < 8; ++m)
            #pragma unroll
            for (int n = 0; n < 4; ++n)
                acc[m][n] = __builtin_amdgcn_mfma_f32_16x16x32_bf16(af[m], bfr[n], acc[m][n], 0, 0, 0);
        __builtin_amdgcn_s_setprio(0);
    }
#undef STAGE256

    int ccol = bcol + wc * 64 + (lane & 15);
    int crow = brow + wr * 128 + ((lane >> 4) << 2);
    #pragma unroll
    for (int n = 0; n < 4; ++n) {
        float bv = bias[ccol + n * 16];
        #pragma unroll
        for (int m = 0; m < 8; ++m) {
            #pragma unroll
            for (int q2 = 0; q2 < 4; ++q2) {
                float v = acc[m][n][q2] + bv;
                C[(size_t)(crow + m * 16 + q2) * N + ccol + n * 16] = v;
            }
        }
    }
}

// ---------------------------------------------------------------------------
extern "C" void kernel_launch(void* const* d_in, const int* in_sizes, int n_in,
                              void* d_out, int out_size, void* d_ws, size_t ws_size,
                              hipStream_t stream) {
    const int*   x    = (const int*)d_in[0];
    const float* emb  = (const float*)d_in[1];
    const float* pos  = (const float*)d_in[2];
    const float* Wq1  = (const float*)d_in[3];
    const float* Wk1  = (const float*)d_in[4];
    const float* Wq2  = (const float*)d_in[5];
    const float* Wk2  = (const float*)d_in[6];
    const float* Wq3  = (const float*)d_in[7];
    const float* Wk3  = (const float*)d_in[8];
    const float* W2   = (const float*)d_in[9];
    const float* b2   = (const float*)d_in[10];
    const float* W3   = (const float*)d_in[11];
    const float* b3   = (const float*)d_in[12];
    const float* W4   = (const float*)d_in[13];
    const float* b4   = (const float*)d_in[14];
    const float* Wout = (const float*)d_in[15];
    const float* bout = (const float*)d_in[16];
    const float* ln2g = (const float*)d_in[17];
    const float* ln2b = (const float*)d_in[18];
    const float* ln3g = (const float*)d_in[19];
    const float* ln3b = (const float*)d_in[20];

    char* wsp = (char*)d_ws;
    float* pa  = (float*)wsp;                    wsp += (size_t)NROWS * MM * 4;
    float* pb  = (float*)wsp;                    wsp += (size_t)NROWS * MM * 4;
    float* dvec = (float*)wsp;                   wsp += 192 * 4;
    float* cvec = (float*)wsp;                   wsp += 192 * 4;
    unsigned int* flg = (unsigned int*)wsp;      wsp += 8 * 4;
    __hip_bfloat16* spkb = (__hip_bfloat16*)wsp; wsp += (size_t)NROWS * HH * 2;
    __hip_bfloat16* hb   = (__hip_bfloat16*)wsp; wsp += (size_t)NROWS * HH * 2;
    __hip_bfloat16* Wqkt = (__hip_bfloat16*)wsp; wsp += (size_t)3 * 64 * HH * 2;
    __hip_bfloat16* W2t  = (__hip_bfloat16*)wsp; wsp += (size_t)HH * HH * 2;
    __hip_bfloat16* W3t  = (__hip_bfloat16*)wsp; wsp += (size_t)HH * HH * 2;
    __hip_bfloat16* W4t  = (__hip_bfloat16*)wsp; wsp += (size_t)HH * HH * 2;
    __hip_bfloat16* Wot  = (__hip_bfloat16*)wsp; wsp += (size_t)NVOCAB * HH * 2;
    float* out = (float*)d_out;

    // flg bits: [0]=spk L1, [1]=hb L1, [2]=spk L2, [3]=hb L2, [4]=spk L3,
    //           [5]=hb L3 (gates cvt_v4 + gemm_big)

    // merged setup (block 0 zeroes flags)
    k_setup<<<6 + 3072, 256, 0, stream>>>(Wq1, Wk1, Wq2, Wk2, Wq3, Wk3,
                                          ln2g, ln2b, ln3g, ln3b,
                                          W2, W3, W4,
                                          Wqkt, dvec, cvec, flg, W2t, W3t, W4t);

    dim3 gmid(HH / 128, NROWS / 128);          // (cols=8, rows=32)
    dim3 gout(NVOCAB / 256, NROWS / 256);      // (cols=125, rows=16) col-fastest

    // layer 1 (embed fused into projmm)
    k_projmm<0><<<NROWS / 64, 256, 0, stream>>>(x, emb, pos, nullptr, Wqkt,
                                                nullptr, nullptr, nullptr, pa, pb);
    k_scan<<<128, 64, 0, stream>>>(pa, pb, spkb, flg + 0);
    k_gemm_bf16<<<gmid, 256, 0, stream>>>(spkb, W2t, b2, hb, HH, HH, flg + 0, flg + 1);

    // layer 2
    k_projmm<1><<<NROWS / 64, 256, 0, stream>>>(nullptr, nullptr, nullptr, hb,
                                                Wqkt + (size_t)64 * HH,
                                                dvec + 64, cvec + 64, flg + 1, pa, pb);
    k_scan<<<128, 64, 0, stream>>>(pa, pb, spkb, flg + 2);
    k_gemm_bf16<<<gmid, 256, 0, stream>>>(spkb, W3t, b3, hb, HH, HH, flg + 2, flg + 3);

    // layer 3
    k_projmm<1><<<NROWS / 64, 256, 0, stream>>>(nullptr, nullptr, nullptr, hb,
                                                Wqkt + (size_t)128 * HH,
                                                dvec + 128, cvec + 128, flg + 3, pa, pb);
    k_scan<<<128, 64, 0, stream>>>(pa, pb, spkb, flg + 4);
    k_gemm_bf16<<<gmid, 256, 0, stream>>>(spkb, W4t, b4, hb, HH, HH, flg + 4, flg + 5);

    // Wout transpose — gated (500-block strip loop; ~1 us when silent)
    k_transpose_cvt_v4<<<NVOCAB / 64 / 32, 256, 0, stream>>>(Wout, Wot, HH, NVOCAB, flg + 5);

    // output projection (activity-gated)
    k_gemm_big<<<gout, 512, 0, stream>>>(hb, Wot, bout, out, NVOCAB, HH, flg + 5);
}